// Round 1
// baseline (525.991 us; speedup 1.0000x reference)
//
#include <hip/hip_runtime.h>

// Unfold (im2col) disguised as depthwise conv with eye(9) kernels.
// x: [16, 64, 112, 112] f32 -> out: [16, 64*9, 112, 112] f32
// out[n, c*9 + (kr*3+kc), h, w] = x[n, c, h+kr-1, w+kc-1] (zero pad)
//
// R4: plane-copy restructure. Each output plane (n, c*9+j) is a shifted
// copy of input plane (n,c). One block per output plane: stream-read
// 50KB (aligned float4 + edge scalar), stream-write 50KB contiguous with
// PLAIN stores (no nontemporal — the harness fill proves plain stores
// hit 78% peak on this buffer). Each wave: 1 read stream + 1 write
// stream (memcpy-shaped), vs R3's 12 interleaved streams/wave.
// XCD-chunked bijective swizzle (9216 % 8 == 0) keeps the 9 j-planes of
// each (n,c) on one XCD so the 9x input re-read is L2-local.

#define NN 16
#define CC 64
#define HH 112
#define WW 112
#define W4C 28                 // float4 per row
#define PLANE  (HH * WW)       // 12544 floats per plane
#define PLANE4 (HH * W4C)      // 3136 float4 per plane
#define NPLANES (NN * CC * 9)  // 9216 output planes

typedef float v4f __attribute__((ext_vector_type(4)));

__global__ __launch_bounds__(256) void unfold9_planes(const float* __restrict__ x,
                                                      float* __restrict__ out) {
    // Bijective XCD-chunked swizzle: consecutive blockIdx round-robin the
    // 8 XCDs, so give XCD k the contiguous plane chunk [k*1152, (k+1)*1152).
    unsigned bid = blockIdx.x;
    unsigned p = (bid & 7u) * (NPLANES / 8u) + (bid >> 3);   // plane 0..9215

    unsigned cj = p % (CC * 9);            // channel index c*9 + j
    unsigned n  = p / (CC * 9);
    unsigned c  = cj / 9u;
    unsigned j  = cj % 9u;
    int dh = (int)(j / 3u) - 1;            // row shift  (kr-1), uniform per block
    int dw = (int)(j % 3u) - 1;            // col shift  (kc-1), uniform per block

    const float* __restrict__ xp = x + ((size_t)n * CC + c) * PLANE;
    float* __restrict__ op = out + (size_t)p * PLANE;

    // 3136 float4 per plane, 256 threads: 12 full sweeps + 64-thread tail.
    for (unsigned pos = threadIdx.x; pos < PLANE4; pos += 256u) {
        unsigned h  = pos / W4C;
        unsigned w4 = pos % W4C;
        int sh = (int)h + dh;
        v4f v;
        if (sh < 0 || sh >= HH) {
            v = (v4f){0.f, 0.f, 0.f, 0.f};          // zero-pad row
        } else {
            const float* __restrict__ row = xp + (unsigned)sh * WW;
            unsigned wb = w4 * 4u;
            v4f m = *reinterpret_cast<const v4f*>(row + wb);   // aligned 16B
            if (dw == 0) {
                v = m;
            } else if (dw < 0) {                    // out[w] = x[w-1]
                float l = (w4 > 0u) ? row[wb - 1u] : 0.f;
                v = (v4f){l, m.x, m.y, m.z};
            } else {                                // out[w] = x[w+1]
                float r = (w4 < W4C - 1u) ? row[wb + 4u] : 0.f;
                v = (v4f){m.y, m.z, m.w, r};
            }
        }
        *reinterpret_cast<v4f*>(op + (size_t)pos * 4u) = v;
    }
}

extern "C" void kernel_launch(void* const* d_in, const int* in_sizes, int n_in,
                              void* d_out, int out_size, void* d_ws, size_t ws_size,
                              hipStream_t stream) {
    const float* x = (const float*)d_in[0];
    // d_in[1] (eye-kernel weight) is baked into the index math.
    float* out = (float*)d_out;
    unfold9_planes<<<NPLANES, 256, 0, stream>>>(x, out);
}

// Round 2
// 486.672 us; speedup vs baseline: 1.0808x; 1.0808x over previous
//
#include <hip/hip_runtime.h>

// Unfold (im2col) disguised as depthwise conv with eye(9) kernels.
// x: [16, 64, 112, 112] f32 -> out: [16, 64*9, 112, 112] f32
// out[n, c*9 + (kr*3+kc), h, w] = x[n, c, h+kr-1, w+kc-1] (zero pad)
//
// R5 = R3 structure EXACTLY, single variable changed: nontemporal stores
// -> PLAIN stores. Rationale: the harness's own fill kernel hits 6.28 TB/s
// (78% peak) on this very output buffer with plain stores; R3's NT stores
// plateau the kernel at ~2.5-2.8 TB/s effective. NT was adopted in R2->R3
// only to make it compile, never A/B'd. R4's plain-store regression was
// confounded by its 9x cache re-read structure (L2 write-allocate churn
// evicted the input planes); R3's input reuse is register/L1-local, so
// plain-store L2 pollution cannot hurt it.
//
// One thread per (n, c, h, w4) produces all 9 kernel-offset outputs from
// 3 input rows held in registers: 3x dwordx4 + 6 edge scalar loads per
// nine 16B plain stores. Writes per wave per j: exactly 1KB contiguous,
// plane-aligned (3136 float4/plane = 49 waves, no straddle).

#define NN 16
#define CC 64
#define HH 112
#define WW 112
#define W4C 28                 // float4 per row
#define PLANE4 (HH * W4C)      // 3136 float4 per output plane

typedef float v4f __attribute__((ext_vector_type(4)));

__global__ __launch_bounds__(256) void unfold9_kernel(const float* __restrict__ x,
                                                      v4f* __restrict__ out,
                                                      unsigned total) {
    unsigned idx = blockIdx.x * 256u + threadIdx.x;
    if (idx >= total) return;

    unsigned w4 = idx % W4C;
    unsigned t  = idx / W4C;
    unsigned h  = t % HH;
    t /= HH;
    unsigned c  = t % CC;
    unsigned n  = t / CC;

    const float* __restrict__ xc = x + (((size_t)n * CC + c) * HH) * WW;
    unsigned wbase = w4 * 4u;

    v4f   mid[3];
    float lft[3], rgt[3];
#pragma unroll
    for (int kr = 0; kr < 3; ++kr) {
        int sh = (int)h + kr - 1;
        bool ok = (sh >= 0) && (sh < HH);
        const float* __restrict__ row = xc + (unsigned)(ok ? sh : 0) * WW;  // clamped: always safe
        // Unconditional loads from the clamped row, then select to zero —
        // only h=0 / h=111 waves are affected.
        v4f   m = *reinterpret_cast<const v4f*>(row + wbase);
        float l = (w4 > 0u)        ? row[wbase - 1u] : 0.f;
        float r = (w4 < W4C - 1u)  ? row[wbase + 4u] : 0.f;
        if (!ok) { m = (v4f){0.f, 0.f, 0.f, 0.f}; l = 0.f; r = 0.f; }
        mid[kr] = m; lft[kr] = l; rgt[kr] = r;
    }

    // out float4 index for j=0; successive j-planes are PLANE4 apart.
    size_t base = ((size_t)n * (CC * 9) + (size_t)c * 9) * PLANE4
                + (size_t)h * W4C + w4;
#pragma unroll
    for (int kr = 0; kr < 3; ++kr) {
        v4f m = mid[kr];
        v4f a = (v4f){lft[kr], m.x, m.y, m.z};   // kc=0: out[w] = x[w-1]
        v4f b = m;                               // kc=1: identity
        v4f d = (v4f){m.y, m.z, m.w, rgt[kr]};   // kc=2: out[w] = x[w+1]
        out[base + (size_t)(kr * 3 + 0) * PLANE4] = a;
        out[base + (size_t)(kr * 3 + 1) * PLANE4] = b;
        out[base + (size_t)(kr * 3 + 2) * PLANE4] = d;
    }
}

extern "C" void kernel_launch(void* const* d_in, const int* in_sizes, int n_in,
                              void* d_out, int out_size, void* d_ws, size_t ws_size,
                              hipStream_t stream) {
    const float* x = (const float*)d_in[0];
    // d_in[1] (eye-kernel weight) is baked into the index math.
    v4f* out = (v4f*)d_out;

    const unsigned total = (unsigned)(NN * CC * HH * W4C);  // 3,211,264 threads
    const unsigned blocks = (total + 255u) / 256u;          // 12,544 blocks
    unfold9_kernel<<<blocks, 256, 0, stream>>>(x, out, total);
}